// Round 3
// baseline (589.088 us; speedup 1.0000x reference)
//
#include <hip/hip_runtime.h>

typedef __attribute__((ext_vector_type(8))) __bf16 bf16x8;
typedef __attribute__((ext_vector_type(4))) float f32x4;
typedef __attribute__((ext_vector_type(8))) unsigned short u16x8;
typedef __attribute__((ext_vector_type(4))) unsigned short u16x4;

#define B_SZ 512

static __device__ __forceinline__ float bf2f(unsigned short u) {
    unsigned int x = ((unsigned int)u) << 16;
    return __builtin_bit_cast(float, x);
}
static __device__ __forceinline__ unsigned short f2bf(float f) {
    unsigned int x = __builtin_bit_cast(unsigned int, f);
    x += 0x7FFFu + ((x >> 16) & 1u);
    return (unsigned short)(x >> 16);
}

// ---------------------------------------------------------------------------
// K0: detect idx element width. int64 (values < 50000) -> all odd int32 words
// zero. int32 real data -> some odd word nonzero. flag=1 -> int32.
// flag pre-zeroed by hipMemsetAsync. Reads exactly the first 512 KB.
// ---------------------------------------------------------------------------
__global__ __launch_bounds__(256) void detect_kernel(const int4* __restrict__ idx4,
                                                     int* __restrict__ flag) {
    int t = blockIdx.x * 256 + threadIdx.x;
    int any = 0;
#pragma unroll
    for (int r = 0; r < 2; r++) {
        int4 v = idx4[t + r * 16384];  // 32768 int4 = 512 KB
        any |= (v.y | v.w);
    }
    if (any) atomicOr(flag, 1);
}

// ---------------------------------------------------------------------------
// K1: streaming, full occupancy (proven ~80% HBM in earlier rounds).
// A (f32 [512,256,512]) -> a2 = A[:,:,:256]+A[:,:,256:] (bf16, row-major)
// plus d[row] = 1/sqrt(rowsum(a2_f32) + 1). One wave per row.
// ---------------------------------------------------------------------------
__global__ __launch_bounds__(256) void rowsum_kernel(const float* __restrict__ A,
                                                     unsigned short* __restrict__ a2,
                                                     float* __restrict__ d) {
    int row = blockIdx.x * 4 + (threadIdx.x >> 6);
    int lane = threadIdx.x & 63;
    const float* p = A + (size_t)row * 512 + lane * 4;
    f32x4 vin = *(const f32x4*)p;
    f32x4 vout = *(const f32x4*)(p + 256);
    f32x4 v = vin + vout;
    float s = v[0] + v[1] + v[2] + v[3];
    u16x4 pk;
#pragma unroll
    for (int e = 0; e < 4; e++) pk[e] = f2bf(v[e]);
    *(u16x4*)(a2 + (size_t)row * 256 + lane * 4) = pk;
#pragma unroll
    for (int m = 32; m >= 1; m >>= 1) s += __shfl_xor(s, m, 64);
    if (lane == 0) d[row] = 1.0f / sqrtf(s + 1.0f);  // rowsum >= 1, never inf
}

// ---------------------------------------------------------------------------
// K2: per-batch block, 512 thr = 8 waves; wave w owns m-strip rows
// w*32..w*32+31 x all 128 h. LDS = ONE 64 KB h-panel (+1 KB d) -> 2 blocks/CU,
// 4 waves/SIMD, all 512 blocks co-resident (single round).
// Amix fragments built in registers from GLOBAL a2 reads (u16x8 at
// rows r..r+15 x 64 B per wave instr = 16 full lines; each a2 byte read once
// per block), mix applied on the fly with d from LDS.
// Panel region reused h0 -> h1 (barrier-separated, round-1 pattern).
// Phases: dL store + early emb issue |bar| frags | panel(ev) |bar|
//         hop1 |bar| h1 write |bar| hop2 | epilogue.
// ---------------------------------------------------------------------------
__global__ __launch_bounds__(512, 4) void main_kernel(const int* __restrict__ idx,
                                                      const unsigned short* __restrict__ a2,
                                                      const float* __restrict__ dG,
                                                      const float* __restrict__ emb,
                                                      const int* __restrict__ flag,
                                                      float* __restrict__ outF) {
    __shared__ __align__(16) unsigned char smem[66560];  // 64K panel + 1K d
    float* dL = (float*)(smem + 65536);

    int b = blockIdx.x;
    int tid = threadIdx.x;
    int w = tid >> 6;  // wave id = m-strip
    int lane = tid & 63;
    int q = lane >> 4;
    int ln = lane & 15;

    if (tid < 256) dL[tid] = dG[b * 256 + tid];

    // ---- early gather issue: emb rows in flight across the frag phase ----
    int j = tid & 255;
    int hh = tid >> 8;  // h-half: 0 or 1
    int pos = b * 256 + j;
    int node = (flag[0] != 0) ? idx[pos] : idx[2 * pos];  // int64: low word
    const float* erow = emb + (size_t)node * 128 + hh * 64;
    f32x4 ev[16];
#pragma unroll
    for (int p = 0; p < 16; p++) ev[p] = *(const f32x4*)(erow + p * 4);

    __syncthreads();  // dL visible

    // ---- Amix fragments in registers (global a2 + on-the-fly mix) ----
    // afr[mt][s]: rows w*32+mt*16+ln, k-cols s*32+q*8..+7 (MFMA A layout)
    const unsigned short* Ab = a2 + (size_t)b * 256 * 256;
    bf16x8 afr[2][8];
#pragma unroll
    for (int s = 0; s < 8; s++) {
        f32x4 dc0 = *(const f32x4*)(dL + s * 32 + q * 8);
        f32x4 dc1 = *(const f32x4*)(dL + s * 32 + q * 8 + 4);
#pragma unroll
        for (int mt = 0; mt < 2; mt++) {
            int r = w * 32 + mt * 16 + ln;
            u16x8 a = *(const u16x8*)(Ab + r * 256 + s * 32 + q * 8);
            float dr = dL[r];
            u16x8 o;
#pragma unroll
            for (int e = 0; e < 8; e++) {
                int c = s * 32 + q * 8 + e;
                float av = bf2f(a[e]);
                bool diag = (r == c);
                if (diag) av += 1.0f;
                float na = av * dr * ((e < 4) ? dc0[e] : dc1[e - 4]);
                float v = 0.8f * na;
                if (diag) v += 0.1f * (1.0f - na);
                o[e] = f2bf(v);
            }
            afr[mt][s] = __builtin_bit_cast(bf16x8, o);
        }
    }

    // ---- h0 panel [h][j] into smem[0..65536), swizzled byte ^= (h&7)<<4 ----
    // wave covers 64 consecutive j at fixed h -> 128 B contiguous per h-step
#pragma unroll
    for (int p = 0; p < 16; p++) {
#pragma unroll
        for (int e = 0; e < 4; e++) {
            int h = hh * 64 + p * 4 + e;
            int byte_ = ((h << 9) + (j << 1)) ^ ((h & 7) << 4);
            *(unsigned short*)(smem + byte_) = f2bf(ev[p][e]);
        }
    }
    __syncthreads();  // h0 panel visible

    f32x4 acc[2][8];
#pragma unroll
    for (int mt = 0; mt < 2; mt++)
#pragma unroll
        for (int nt = 0; nt < 8; nt++) acc[mt][nt] = f32x4{0.f, 0.f, 0.f, 0.f};

    // ---- hop 1: acc = Amix(reg) @ h0(LDS) ----
#pragma unroll
    for (int s = 0; s < 8; s++) {
        bf16x8 bfr[8];
#pragma unroll
        for (int nt = 0; nt < 8; nt++) {
            int h = nt * 16 + ln;
            int byte_ = ((h << 9) + s * 64 + q * 16) ^ ((h & 7) << 4);
            bfr[nt] = *(const bf16x8*)(smem + byte_);
        }
#pragma unroll
        for (int mt = 0; mt < 2; mt++)
#pragma unroll
            for (int nt = 0; nt < 8; nt++)
                acc[mt][nt] = __builtin_amdgcn_mfma_f32_16x16x32_bf16(
                    afr[mt][s], bfr[nt], acc[mt][nt], 0, 0, 0);
    }
    __syncthreads();  // all h0 reads done -> region reusable

    // ---- h1 -> same region, layout [h][i], same swizzle ----
    // C/D layout: col(h)=ln, row(i)=q*4+reg -> i-consecutive u16x4
#pragma unroll
    for (int mt = 0; mt < 2; mt++)
#pragma unroll
        for (int nt = 0; nt < 8; nt++) {
            int h = nt * 16 + ln;
            int i0 = w * 32 + mt * 16 + q * 4;
            u16x4 pk;
#pragma unroll
            for (int r = 0; r < 4; r++) pk[r] = f2bf(acc[mt][nt][r]);
            int byte_ = ((h << 9) + (i0 << 1)) ^ ((h & 7) << 4);
            *(u16x4*)(smem + byte_) = pk;
            acc[mt][nt] = f32x4{0.f, 0.f, 0.f, 0.f};
        }
    __syncthreads();  // h1 visible

    // ---- hop 2: acc = Amix(reg) @ h1(LDS) ----
#pragma unroll
    for (int s = 0; s < 8; s++) {
        bf16x8 bfr[8];
#pragma unroll
        for (int nt = 0; nt < 8; nt++) {
            int h = nt * 16 + ln;
            int byte_ = ((h << 9) + s * 64 + q * 16) ^ ((h & 7) << 4);
            bfr[nt] = *(const bf16x8*)(smem + byte_);
        }
#pragma unroll
        for (int mt = 0; mt < 2; mt++)
#pragma unroll
            for (int nt = 0; nt < 8; nt++)
                acc[mt][nt] = __builtin_amdgcn_mfma_f32_16x16x32_bf16(
                    afr[mt][s], bfr[nt], acc[mt][nt], 0, 0, 0);
    }

    // ---- epilogue: out[b, i, h] fp32 (16 lanes ln -> 64 B contiguous) ----
#pragma unroll
    for (int mt = 0; mt < 2; mt++)
#pragma unroll
        for (int nt = 0; nt < 8; nt++) {
            int h = nt * 16 + ln;
            int i0 = w * 32 + mt * 16 + q * 4;
#pragma unroll
            for (int r = 0; r < 4; r++)
                outF[((size_t)b * 256 + i0 + r) * 128 + h] = acc[mt][nt][r];
        }
}

extern "C" void kernel_launch(void* const* d_in, const int* in_sizes, int n_in,
                              void* d_out, int out_size, void* d_ws, size_t ws_size,
                              hipStream_t stream) {
    const int* idx = (const int*)d_in[0];      // [512,256] int32 or int64
    const float* A = (const float*)d_in[1];    // [512,256,512] f32
    const float* emb = (const float*)d_in[2];  // [50000,128] f32
    float* out = (float*)d_out;                // [512,256,128] f32

    char* ws = (char*)d_ws;
    int* flag = (int*)ws;                                 // 4 B
    float* d = (float*)(ws + 4096);                       // 512 KB
    unsigned short* a2 = (unsigned short*)(ws + 528384);  // 64 MB bf16

    hipMemsetAsync(flag, 0, 4, stream);
    detect_kernel<<<64, 256, 0, stream>>>((const int4*)idx, flag);
    rowsum_kernel<<<B_SZ * 256 / 4, 256, 0, stream>>>(A, a2, d);
    main_kernel<<<B_SZ, 512, 0, stream>>>(idx, a2, d, emb, flag, out);
}

// Round 4
// 539.384 us; speedup vs baseline: 1.0921x; 1.0921x over previous
//
#include <hip/hip_runtime.h>

typedef __attribute__((ext_vector_type(8))) __bf16 bf16x8;
typedef __attribute__((ext_vector_type(4))) float f32x4;
typedef __attribute__((ext_vector_type(8))) unsigned short u16x8;
typedef __attribute__((ext_vector_type(4))) unsigned short u16x4;

#define B_SZ 512

static __device__ __forceinline__ float bf2f(unsigned short u) {
    unsigned int x = ((unsigned int)u) << 16;
    return __builtin_bit_cast(float, x);
}
static __device__ __forceinline__ unsigned short f2bf(float f) {
    unsigned int x = __builtin_bit_cast(unsigned int, f);
    x += 0x7FFFu + ((x >> 16) & 1u);
    return (unsigned short)(x >> 16);
}

// ---------------------------------------------------------------------------
// K0: detect idx element width. int64 (values < 50000) -> all odd int32 words
// zero. int32 real data -> some odd word nonzero. flag=1 -> int32.
// flag pre-zeroed by hipMemsetAsync. Reads exactly the first 512 KB.
// ---------------------------------------------------------------------------
__global__ __launch_bounds__(256) void detect_kernel(const int4* __restrict__ idx4,
                                                     int* __restrict__ flag) {
    int t = blockIdx.x * 256 + threadIdx.x;
    int any = 0;
#pragma unroll
    for (int r = 0; r < 2; r++) {
        int4 v = idx4[t + r * 16384];  // 32768 int4 = 512 KB
        any |= (v.y | v.w);
    }
    if (any) atomicOr(flag, 1);
}

// ---------------------------------------------------------------------------
// K1: streaming, full occupancy (~80% HBM proven).
// A (f32 [512,256,512]) -> a2 = A[:,:,:256]+A[:,:,256:] (bf16, row-major)
// plus d[row] = 1/sqrt(rowsum + 1). One wave per row.
// ---------------------------------------------------------------------------
__global__ __launch_bounds__(256) void rowsum_kernel(const float* __restrict__ A,
                                                     unsigned short* __restrict__ a2,
                                                     float* __restrict__ d) {
    int row = blockIdx.x * 4 + (threadIdx.x >> 6);
    int lane = threadIdx.x & 63;
    const float* p = A + (size_t)row * 512 + lane * 4;
    f32x4 vin = *(const f32x4*)p;
    f32x4 vout = *(const f32x4*)(p + 256);
    f32x4 v = vin + vout;
    float s = v[0] + v[1] + v[2] + v[3];
    u16x4 pk;
#pragma unroll
    for (int e = 0; e < 4; e++) pk[e] = f2bf(v[e]);
    *(u16x4*)(a2 + (size_t)row * 256 + lane * 4) = pk;
#pragma unroll
    for (int m = 32; m >= 1; m >>= 1) s += __shfl_xor(s, m, 64);
    if (lane == 0) d[row] = 1.0f / sqrtf(s + 1.0f);  // rowsum >= 1, never inf
}

// ---------------------------------------------------------------------------
// K2: per-batch block, 512 thr = 8 waves; wave w owns m-strip rows
// w*32..+31 x all 128 h. LDS = 64 KB h-panel + 1 KB d -> 2 blocks/CU.
// REGISTER SCHEDULE (the round-3 spill fix):
//   phase 0: dL store + emb loads (ev 64 VGPR) -> panel write (ev DIES)
//   |bar|
//   phase 1: araw[2][8] global a2 loads (64) -> mix -> afr[2][8] (32)
//   phase 2: hop1, bfr chunked 4-wide (afr 32 + acc 64 + bfr 16 ~ 120)
//   |bar| h1 write |bar| hop2 | epilogue
// Peak live ~120 VGPR < 128 cap from __launch_bounds__(512,4): no spill.
// ---------------------------------------------------------------------------
__global__ __launch_bounds__(512, 4) void main_kernel(const int* __restrict__ idx,
                                                      const unsigned short* __restrict__ a2,
                                                      const float* __restrict__ dG,
                                                      const float* __restrict__ emb,
                                                      const int* __restrict__ flag,
                                                      float* __restrict__ outF) {
    __shared__ __align__(16) unsigned char smem[66560];  // 64K panel + 1K d
    float* dL = (float*)(smem + 65536);

    int b = blockIdx.x;
    int tid = threadIdx.x;
    int w = tid >> 6;  // wave id = m-strip
    int lane = tid & 63;
    int q = lane >> 4;
    int ln = lane & 15;

    if (tid < 256) dL[tid] = dG[b * 256 + tid];

    // ---- phase 0: gather emb rows and write h0 panel NOW (ev dies here) ----
    {
        int j = tid & 255;
        int hh = tid >> 8;  // h-half: 0 or 1
        int pos = b * 256 + j;
        int node = (flag[0] != 0) ? idx[pos] : idx[2 * pos];  // int64: low word
        const float* erow = emb + (size_t)node * 128 + hh * 64;
        f32x4 ev[16];
#pragma unroll
        for (int p = 0; p < 16; p++) ev[p] = *(const f32x4*)(erow + p * 4);
        // panel [h][j], swizzled byte ^= (h&7)<<4; 64 lanes x 2B = 128 B span
#pragma unroll
        for (int p = 0; p < 16; p++) {
#pragma unroll
            for (int e = 0; e < 4; e++) {
                int h = hh * 64 + p * 4 + e;
                int byte_ = ((h << 9) + (j << 1)) ^ ((h & 7) << 4);
                *(unsigned short*)(smem + byte_) = f2bf(ev[p][e]);
            }
        }
    }
    __syncthreads();  // dL + h0 panel visible

    // ---- phase 1: Amix fragments from GLOBAL a2 (coalesced: 16 rows x 64 B
    // per wave instr), mix applied on the fly ----
    const unsigned short* Ab = a2 + (size_t)b * 256 * 256;
    u16x8 araw[2][8];
#pragma unroll
    for (int s = 0; s < 8; s++)
#pragma unroll
        for (int mt = 0; mt < 2; mt++) {
            int r = w * 32 + mt * 16 + ln;
            araw[mt][s] = *(const u16x8*)(Ab + r * 256 + s * 32 + q * 8);
        }
    bf16x8 afr[2][8];
#pragma unroll
    for (int s = 0; s < 8; s++) {
        f32x4 dc0 = *(const f32x4*)(dL + s * 32 + q * 8);
        f32x4 dc1 = *(const f32x4*)(dL + s * 32 + q * 8 + 4);
#pragma unroll
        for (int mt = 0; mt < 2; mt++) {
            int r = w * 32 + mt * 16 + ln;
            float dr = dL[r];
            u16x8 a = araw[mt][s];
            u16x8 o;
#pragma unroll
            for (int e = 0; e < 8; e++) {
                int c = s * 32 + q * 8 + e;
                float av = bf2f(a[e]);
                bool diag = (r == c);
                if (diag) av += 1.0f;
                float na = av * dr * ((e < 4) ? dc0[e] : dc1[e - 4]);
                float v = 0.8f * na;
                if (diag) v += 0.1f * (1.0f - na);
                o[e] = f2bf(v);
            }
            afr[mt][s] = __builtin_bit_cast(bf16x8, o);
        }
    }

    f32x4 acc[2][8];
#pragma unroll
    for (int mt = 0; mt < 2; mt++)
#pragma unroll
        for (int nt = 0; nt < 8; nt++) acc[mt][nt] = f32x4{0.f, 0.f, 0.f, 0.f};

    // ---- hop 1: acc = Amix(reg) @ h0(LDS); bfr chunked 4-wide ----
#pragma unroll
    for (int s = 0; s < 8; s++) {
#pragma unroll
        for (int half = 0; half < 2; half++) {
            bf16x8 bfr[4];
#pragma unroll
            for (int t4 = 0; t4 < 4; t4++) {
                int h = (half * 4 + t4) * 16 + ln;
                int byte_ = ((h << 9) + s * 64 + q * 16) ^ ((h & 7) << 4);
                bfr[t4] = *(const bf16x8*)(smem + byte_);
            }
#pragma unroll
            for (int mt = 0; mt < 2; mt++)
#pragma unroll
                for (int t4 = 0; t4 < 4; t4++)
                    acc[mt][half * 4 + t4] = __builtin_amdgcn_mfma_f32_16x16x32_bf16(
                        afr[mt][s], bfr[t4], acc[mt][half * 4 + t4], 0, 0, 0);
        }
    }
    __syncthreads();  // all h0 reads done -> region reusable

    // ---- h1 -> same region, layout [h][i], same swizzle ----
    // C/D layout: col(h)=ln, row(i)=q*4+reg -> i-consecutive u16x4
#pragma unroll
    for (int mt = 0; mt < 2; mt++)
#pragma unroll
        for (int nt = 0; nt < 8; nt++) {
            int h = nt * 16 + ln;
            int i0 = w * 32 + mt * 16 + q * 4;
            u16x4 pk;
#pragma unroll
            for (int r = 0; r < 4; r++) pk[r] = f2bf(acc[mt][nt][r]);
            int byte_ = ((h << 9) + (i0 << 1)) ^ ((h & 7) << 4);
            *(u16x4*)(smem + byte_) = pk;
            acc[mt][nt] = f32x4{0.f, 0.f, 0.f, 0.f};
        }
    __syncthreads();  // h1 visible

    // ---- hop 2: acc = Amix(reg) @ h1(LDS) ----
#pragma unroll
    for (int s = 0; s < 8; s++) {
#pragma unroll
        for (int half = 0; half < 2; half++) {
            bf16x8 bfr[4];
#pragma unroll
            for (int t4 = 0; t4 < 4; t4++) {
                int h = (half * 4 + t4) * 16 + ln;
                int byte_ = ((h << 9) + s * 64 + q * 16) ^ ((h & 7) << 4);
                bfr[t4] = *(const bf16x8*)(smem + byte_);
            }
#pragma unroll
            for (int mt = 0; mt < 2; mt++)
#pragma unroll
                for (int t4 = 0; t4 < 4; t4++)
                    acc[mt][half * 4 + t4] = __builtin_amdgcn_mfma_f32_16x16x32_bf16(
                        afr[mt][s], bfr[t4], acc[mt][half * 4 + t4], 0, 0, 0);
        }
    }

    // ---- epilogue: out[b, i, h] fp32 (16 lanes ln -> 64 B contiguous) ----
#pragma unroll
    for (int mt = 0; mt < 2; mt++)
#pragma unroll
        for (int nt = 0; nt < 8; nt++) {
            int h = nt * 16 + ln;
            int i0 = w * 32 + mt * 16 + q * 4;
#pragma unroll
            for (int r = 0; r < 4; r++)
                outF[((size_t)b * 256 + i0 + r) * 128 + h] = acc[mt][nt][r];
        }
}

extern "C" void kernel_launch(void* const* d_in, const int* in_sizes, int n_in,
                              void* d_out, int out_size, void* d_ws, size_t ws_size,
                              hipStream_t stream) {
    const int* idx = (const int*)d_in[0];      // [512,256] int32 or int64
    const float* A = (const float*)d_in[1];    // [512,256,512] f32
    const float* emb = (const float*)d_in[2];  // [50000,128] f32
    float* out = (float*)d_out;                // [512,256,128] f32

    char* ws = (char*)d_ws;
    int* flag = (int*)ws;                                 // 4 B
    float* d = (float*)(ws + 4096);                       // 512 KB
    unsigned short* a2 = (unsigned short*)(ws + 528384);  // 64 MB bf16

    hipMemsetAsync(flag, 0, 4, stream);
    detect_kernel<<<64, 256, 0, stream>>>((const int4*)idx, flag);
    rowsum_kernel<<<B_SZ * 256 / 4, 256, 0, stream>>>(A, a2, d);
    main_kernel<<<B_SZ, 512, 0, stream>>>(idx, a2, d, emb, flag, out);
}

// Round 5
// 437.507 us; speedup vs baseline: 1.3465x; 1.2329x over previous
//
#include <hip/hip_runtime.h>

typedef __attribute__((ext_vector_type(8))) __bf16 bf16x8;
typedef __attribute__((ext_vector_type(4))) float f32x4;
typedef __attribute__((ext_vector_type(8))) unsigned short u16x8;
typedef __attribute__((ext_vector_type(4))) unsigned short u16x4;

#define B_SZ 512

static __device__ __forceinline__ float bf2f(unsigned short u) {
    unsigned int x = ((unsigned int)u) << 16;
    return __builtin_bit_cast(float, x);
}
static __device__ __forceinline__ unsigned short f2bf(float f) {
    unsigned int x = __builtin_bit_cast(unsigned int, f);
    x += 0x7FFFu + ((x >> 16) & 1u);
    return (unsigned short)(x >> 16);
}

// mix one A-fragment: a2 row r, cols cbase..cbase+7 -> bf16 Amix fragment
static __device__ __forceinline__ bf16x8 mixfrag(u16x8 a, int r, int cbase,
                                                 f32x4 dc0, f32x4 dc1, float dr) {
    u16x8 o;
#pragma unroll
    for (int e = 0; e < 8; e++) {
        int c = cbase + e;
        float av = bf2f(a[e]);
        bool diag = (r == c);
        if (diag) av += 1.0f;
        float na = av * dr * ((e < 4) ? dc0[e] : dc1[e - 4]);
        float v = 0.8f * na;
        if (diag) v += 0.1f * (1.0f - na);
        o[e] = f2bf(v);
    }
    return __builtin_bit_cast(bf16x8, o);
}

// ---------------------------------------------------------------------------
// K0: detect idx element width. int64 (values < 50000) -> all odd int32 words
// zero. int32 real data -> some odd word nonzero. flag=1 -> int32.
// ---------------------------------------------------------------------------
__global__ __launch_bounds__(256) void detect_kernel(const int4* __restrict__ idx4,
                                                     int* __restrict__ flag) {
    int t = blockIdx.x * 256 + threadIdx.x;
    int any = 0;
#pragma unroll
    for (int r = 0; r < 2; r++) {
        int4 v = idx4[t + r * 16384];  // 32768 int4 = 512 KB
        any |= (v.y | v.w);
    }
    if (any) atomicOr(flag, 1);
}

// ---------------------------------------------------------------------------
// K1: streaming, full occupancy (~80% HBM proven).
// A (f32 [512,256,512]) -> a2 = A[:,:,:256]+A[:,:,256:] (bf16, row-major)
// plus d[row] = 1/sqrt(rowsum + 1). One wave per row.
// ---------------------------------------------------------------------------
__global__ __launch_bounds__(256) void rowsum_kernel(const float* __restrict__ A,
                                                     unsigned short* __restrict__ a2,
                                                     float* __restrict__ d) {
    int row = blockIdx.x * 4 + (threadIdx.x >> 6);
    int lane = threadIdx.x & 63;
    const float* p = A + (size_t)row * 512 + lane * 4;
    f32x4 vin = *(const f32x4*)p;
    f32x4 vout = *(const f32x4*)(p + 256);
    f32x4 v = vin + vout;
    float s = v[0] + v[1] + v[2] + v[3];
    u16x4 pk;
#pragma unroll
    for (int e = 0; e < 4; e++) pk[e] = f2bf(v[e]);
    *(u16x4*)(a2 + (size_t)row * 256 + lane * 4) = pk;
#pragma unroll
    for (int m = 32; m >= 1; m >>= 1) s += __shfl_xor(s, m, 64);
    if (lane == 0) d[row] = 1.0f / sqrtf(s + 1.0f);  // rowsum >= 1, never inf
}

// ---------------------------------------------------------------------------
// K2: per-batch block, 512 thr = 8 waves; wave w owns m-strip rows w*32..+31
// x all 128 h. LDS = 64 KB h-panel + 1 KB d -> 2 blocks/CU, 4 waves/SIMD.
// SPILL FIX (round 4 post-mortem: bf16x8 = 4 VGPR, afr[2][8] was 64, peak 150
// -> scratch): A-fragments are now STREAMED per k-step in both hops —
// prefetch(16) + af(8) + acc(64) + bfr(16) + dc(8) ~ 112 < 128 cap. Mix is
// recomputed for hop 2 (VALU overlaps MFMA; a2 re-read is L2-warm).
// s-loops are '#pragma unroll 1' so loads cannot be hoisted en masse.
// ---------------------------------------------------------------------------
__global__ __launch_bounds__(512, 4) void main_kernel(const int* __restrict__ idx,
                                                      const unsigned short* __restrict__ a2,
                                                      const float* __restrict__ dG,
                                                      const float* __restrict__ emb,
                                                      const int* __restrict__ flag,
                                                      float* __restrict__ outF) {
    __shared__ __align__(16) unsigned char smem[66560];  // 64K panel + 1K d
    float* dL = (float*)(smem + 65536);

    int b = blockIdx.x;
    int tid = threadIdx.x;
    int w = tid >> 6;  // wave id = m-strip
    int lane = tid & 63;
    int q = lane >> 4;
    int ln = lane & 15;

    if (tid < 256) dL[tid] = dG[b * 256 + tid];

    // ---- phase 0: gather emb rows, write h0 panel (ev dies here) ----
    {
        int j = tid & 255;
        int hh = tid >> 8;  // h-half: 0 or 1
        int pos = b * 256 + j;
        int node = (flag[0] != 0) ? idx[pos] : idx[2 * pos];  // int64: low word
        const float* erow = emb + (size_t)node * 128 + hh * 64;
        f32x4 ev[16];
#pragma unroll
        for (int p = 0; p < 16; p++) ev[p] = *(const f32x4*)(erow + p * 4);
        // panel [h][j] bf16, swizzled byte ^= (h&7)<<4
#pragma unroll
        for (int p = 0; p < 16; p++) {
#pragma unroll
            for (int e = 0; e < 4; e++) {
                int h = hh * 64 + p * 4 + e;
                int byte_ = ((h << 9) + (j << 1)) ^ ((h & 7) << 4);
                *(unsigned short*)(smem + byte_) = f2bf(ev[p][e]);
            }
        }
    }
    __syncthreads();  // dL + h0 panel visible

    const unsigned short* Ab = a2 + (size_t)b * 256 * 256;
    int r0 = w * 32 + ln;
    int r1 = r0 + 16;
    float dr0 = dL[r0];
    float dr1 = dL[r1];

    f32x4 acc[2][8];
#pragma unroll
    for (int mt = 0; mt < 2; mt++)
#pragma unroll
        for (int nt = 0; nt < 8; nt++) acc[mt][nt] = f32x4{0.f, 0.f, 0.f, 0.f};

    // ---- hop 1: acc = Amix(streamed) @ h0(LDS) ----
    {
        u16x8 nxt0 = *(const u16x8*)(Ab + r0 * 256 + q * 8);
        u16x8 nxt1 = *(const u16x8*)(Ab + r1 * 256 + q * 8);
#pragma unroll 1
        for (int s = 0; s < 8; s++) {
            u16x8 cur0 = nxt0, cur1 = nxt1;
            if (s < 7) {
                nxt0 = *(const u16x8*)(Ab + r0 * 256 + (s + 1) * 32 + q * 8);
                nxt1 = *(const u16x8*)(Ab + r1 * 256 + (s + 1) * 32 + q * 8);
            }
            f32x4 dc0 = *(const f32x4*)(dL + s * 32 + q * 8);
            f32x4 dc1 = *(const f32x4*)(dL + s * 32 + q * 8 + 4);
            int cbase = s * 32 + q * 8;
            bf16x8 af0 = mixfrag(cur0, r0, cbase, dc0, dc1, dr0);
            bf16x8 af1 = mixfrag(cur1, r1, cbase, dc0, dc1, dr1);
#pragma unroll
            for (int half = 0; half < 2; half++) {
                bf16x8 bfr[4];
#pragma unroll
                for (int t4 = 0; t4 < 4; t4++) {
                    int h = (half * 4 + t4) * 16 + ln;
                    int byte_ = ((h << 9) + s * 64 + q * 16) ^ ((h & 7) << 4);
                    bfr[t4] = *(const bf16x8*)(smem + byte_);
                }
#pragma unroll
                for (int t4 = 0; t4 < 4; t4++)
                    acc[0][half * 4 + t4] = __builtin_amdgcn_mfma_f32_16x16x32_bf16(
                        af0, bfr[t4], acc[0][half * 4 + t4], 0, 0, 0);
#pragma unroll
                for (int t4 = 0; t4 < 4; t4++)
                    acc[1][half * 4 + t4] = __builtin_amdgcn_mfma_f32_16x16x32_bf16(
                        af1, bfr[t4], acc[1][half * 4 + t4], 0, 0, 0);
            }
        }
    }
    __syncthreads();  // all h0 reads done -> region reusable

    // ---- h1 -> same region, layout [h][i], same swizzle ----
    // C/D layout: col(h)=ln, row(i)=q*4+reg -> i-consecutive u16x4
#pragma unroll
    for (int mt = 0; mt < 2; mt++)
#pragma unroll
        for (int nt = 0; nt < 8; nt++) {
            int h = nt * 16 + ln;
            int i0 = w * 32 + mt * 16 + q * 4;
            u16x4 pk;
#pragma unroll
            for (int r = 0; r < 4; r++) pk[r] = f2bf(acc[mt][nt][r]);
            int byte_ = ((h << 9) + (i0 << 1)) ^ ((h & 7) << 4);
            *(u16x4*)(smem + byte_) = pk;
            acc[mt][nt] = f32x4{0.f, 0.f, 0.f, 0.f};
        }
    __syncthreads();  // h1 visible

    // ---- hop 2: acc = Amix(streamed, re-mixed) @ h1(LDS) ----
    {
        u16x8 nxt0 = *(const u16x8*)(Ab + r0 * 256 + q * 8);
        u16x8 nxt1 = *(const u16x8*)(Ab + r1 * 256 + q * 8);
#pragma unroll 1
        for (int s = 0; s < 8; s++) {
            u16x8 cur0 = nxt0, cur1 = nxt1;
            if (s < 7) {
                nxt0 = *(const u16x8*)(Ab + r0 * 256 + (s + 1) * 32 + q * 8);
                nxt1 = *(const u16x8*)(Ab + r1 * 256 + (s + 1) * 32 + q * 8);
            }
            f32x4 dc0 = *(const f32x4*)(dL + s * 32 + q * 8);
            f32x4 dc1 = *(const f32x4*)(dL + s * 32 + q * 8 + 4);
            int cbase = s * 32 + q * 8;
            bf16x8 af0 = mixfrag(cur0, r0, cbase, dc0, dc1, dr0);
            bf16x8 af1 = mixfrag(cur1, r1, cbase, dc0, dc1, dr1);
#pragma unroll
            for (int half = 0; half < 2; half++) {
                bf16x8 bfr[4];
#pragma unroll
                for (int t4 = 0; t4 < 4; t4++) {
                    int h = (half * 4 + t4) * 16 + ln;
                    int byte_ = ((h << 9) + s * 64 + q * 16) ^ ((h & 7) << 4);
                    bfr[t4] = *(const bf16x8*)(smem + byte_);
                }
#pragma unroll
                for (int t4 = 0; t4 < 4; t4++)
                    acc[0][half * 4 + t4] = __builtin_amdgcn_mfma_f32_16x16x32_bf16(
                        af0, bfr[t4], acc[0][half * 4 + t4], 0, 0, 0);
#pragma unroll
                for (int t4 = 0; t4 < 4; t4++)
                    acc[1][half * 4 + t4] = __builtin_amdgcn_mfma_f32_16x16x32_bf16(
                        af1, bfr[t4], acc[1][half * 4 + t4], 0, 0, 0);
            }
        }
    }

    // ---- epilogue: out[b, i, h] fp32 ----
#pragma unroll
    for (int mt = 0; mt < 2; mt++)
#pragma unroll
        for (int nt = 0; nt < 8; nt++) {
            int h = nt * 16 + ln;
            int i0 = w * 32 + mt * 16 + q * 4;
#pragma unroll
            for (int r = 0; r < 4; r++)
                outF[((size_t)b * 256 + i0 + r) * 128 + h] = acc[mt][nt][r];
        }
}

extern "C" void kernel_launch(void* const* d_in, const int* in_sizes, int n_in,
                              void* d_out, int out_size, void* d_ws, size_t ws_size,
                              hipStream_t stream) {
    const int* idx = (const int*)d_in[0];      // [512,256] int32 or int64
    const float* A = (const float*)d_in[1];    // [512,256,512] f32
    const float* emb = (const float*)d_in[2];  // [50000,128] f32
    float* out = (float*)d_out;                // [512,256,128] f32

    char* ws = (char*)d_ws;
    int* flag = (int*)ws;                                 // 4 B
    float* d = (float*)(ws + 4096);                       // 512 KB
    unsigned short* a2 = (unsigned short*)(ws + 528384);  // 64 MB bf16

    hipMemsetAsync(flag, 0, 4, stream);
    detect_kernel<<<64, 256, 0, stream>>>((const int4*)idx, flag);
    rowsum_kernel<<<B_SZ * 256 / 4, 256, 0, stream>>>(A, a2, d);
    main_kernel<<<B_SZ, 512, 0, stream>>>(idx, a2, d, emb, flag, out);
}